// Round 1
// baseline (1083.430 us; speedup 1.0000x reference)
//
#include <hip/hip_runtime.h>

// Problem constants
#define NDRUG 50000
#define NDIS  50000
#define RR    5
#define FF    128
#define EFFD  128
#define OUTD  64
#define EE    400000
#define NCOL  (RR * OUTD)   // 320 columns in fused g / out layout [n][r*64+o]

// ---------------------------------------------------------------------------
// Kernel A: M[f][r*64+o] = sum_e (att[r,0]*basis[0,f,e] + att[r,1]*basis[1,f,e]) * fc_w[e,o]
// ---------------------------------------------------------------------------
__global__ __launch_bounds__(256) void k_make_M(const float* __restrict__ att,
                                                const float* __restrict__ basis,
                                                const float* __restrict__ fcw,
                                                float* __restrict__ M) {
    int tid = blockIdx.x * 256 + threadIdx.x;
    if (tid >= RR * FF * OUTD) return;
    int r = tid / (FF * OUTD);
    int rem = tid - r * FF * OUTD;
    int f = rem >> 6;
    int o = rem & 63;
    float a0 = att[r * 2 + 0], a1 = att[r * 2 + 1];
    const float* b0 = basis + f * EFFD;
    const float* b1 = basis + FF * EFFD + f * EFFD;
    float acc = 0.f;
#pragma unroll 4
    for (int e = 0; e < EFFD; ++e) {
        float w = a0 * b0[e] + a1 * b1[e];
        acc += w * fcw[e * OUTD + o];
    }
    M[f * NCOL + r * OUTD + o] = acc;
}

// ---------------------------------------------------------------------------
// Kernel B: g[n][col] = cj[n] * sum_k feat[n][k] * M[k][col]   (GEMM 50000x320x128)
// 64x64 tile, 256 threads, 4x4 microtile. blockIdx.z selects drug/dis side.
// ---------------------------------------------------------------------------
__global__ __launch_bounds__(256) void k_gemm(const float* __restrict__ featA,
                                              const float* __restrict__ cjA,
                                              const float* __restrict__ featB,
                                              const float* __restrict__ cjB,
                                              const float* __restrict__ M,
                                              float* __restrict__ gA,
                                              float* __restrict__ gB) {
    const float* feat; const float* cj; float* g;
    if (blockIdx.z == 0) { feat = featA; cj = cjA; g = gA; }
    else                 { feat = featB; cj = cjB; g = gB; }

    __shared__ float As[64][132];   // padded: stride 132 floats (528B, 16B-aligned)
    __shared__ float Bs[128][68];   // padded: stride 68 floats (272B, 16B-aligned)

    const int tid  = threadIdx.x;
    const int row0 = blockIdx.x * 64;
    const int col0 = blockIdx.y * 64;

    // Load A tile: 64 rows x 128 cols (2048 float4)
    for (int i = tid; i < 64 * 32; i += 256) {
        int r  = i >> 5;
        int c4 = (i & 31) << 2;
        float4 v = make_float4(0.f, 0.f, 0.f, 0.f);
        int row = row0 + r;
        if (row < NDRUG) v = *(const float4*)(feat + (size_t)row * FF + c4);
        *(float4*)&As[r][c4] = v;
    }
    // Load B tile: 128 x 64 (2048 float4)
    for (int i = tid; i < 128 * 16; i += 256) {
        int k  = i >> 4;
        int c4 = (i & 15) << 2;
        *(float4*)&Bs[k][c4] = *(const float4*)(M + k * NCOL + col0 + c4);
    }
    __syncthreads();

    const int ty = (tid >> 4) << 2;   // row offset within tile, 0..60
    const int tx = (tid & 15) << 2;   // col offset within tile, 0..60

    float acc[4][4] = {};
#define GSTEP(AI, AC, BV) \
    acc[AI][0] += (AC) * (BV).x; acc[AI][1] += (AC) * (BV).y; \
    acc[AI][2] += (AC) * (BV).z; acc[AI][3] += (AC) * (BV).w;

    for (int k = 0; k < 128; k += 4) {
        float4 a0 = *(const float4*)&As[ty + 0][k];
        float4 a1 = *(const float4*)&As[ty + 1][k];
        float4 a2 = *(const float4*)&As[ty + 2][k];
        float4 a3 = *(const float4*)&As[ty + 3][k];
        float4 b0 = *(const float4*)&Bs[k + 0][tx];
        float4 b1 = *(const float4*)&Bs[k + 1][tx];
        float4 b2 = *(const float4*)&Bs[k + 2][tx];
        float4 b3 = *(const float4*)&Bs[k + 3][tx];
        GSTEP(0, a0.x, b0) GSTEP(0, a0.y, b1) GSTEP(0, a0.z, b2) GSTEP(0, a0.w, b3)
        GSTEP(1, a1.x, b0) GSTEP(1, a1.y, b1) GSTEP(1, a1.z, b2) GSTEP(1, a1.w, b3)
        GSTEP(2, a2.x, b0) GSTEP(2, a2.y, b1) GSTEP(2, a2.z, b2) GSTEP(2, a2.w, b3)
        GSTEP(3, a3.x, b0) GSTEP(3, a3.y, b1) GSTEP(3, a3.z, b2) GSTEP(3, a3.w, b3)
    }
#undef GSTEP

#pragma unroll
    for (int i = 0; i < 4; ++i) {
        int row = row0 + ty + i;
        if (row < NDRUG) {
            float s = cj[row];
            float4 v = make_float4(acc[i][0] * s, acc[i][1] * s, acc[i][2] * s, acc[i][3] * s);
            *(float4*)(g + (size_t)row * NCOL + col0 + tx) = v;
        }
    }
}

// ---------------------------------------------------------------------------
// Kernel C: edge aggregation. One wave per edge; lane o does
//   out[dst][r*64+o] += g[src][r*64+o]   via hardware f32 atomic.
// ---------------------------------------------------------------------------
__global__ __launch_bounds__(256) void k_agg(const float* __restrict__ g,
                                             const int* __restrict__ srcs,
                                             const int* __restrict__ dsts,
                                             float* __restrict__ outp) {
    const int lane = threadIdx.x & 63;
    long long wave = (long long)blockIdx.x * 4 + (threadIdx.x >> 6);
    const long long nw = (long long)gridDim.x * 4;
    const long long NEDGE = (long long)RR * EE;
    for (long long e = wave; e < NEDGE; e += nw) {
        int r   = (int)(e / EE);          // constant divisor -> magic mul
        int src = srcs[e];
        int dst = dsts[e];
        float v = g[(size_t)src * NCOL + r * OUTD + lane];
        unsafeAtomicAdd(outp + (size_t)dst * NCOL + r * OUTD + lane, v);
    }
}

// ---------------------------------------------------------------------------
// Kernel D: epilogue  out[n][col] = out[n][col]*ci[n] + fc_b[col%64]  (float4)
// ---------------------------------------------------------------------------
__global__ __launch_bounds__(256) void k_epi(float* __restrict__ outp,
                                             const float* __restrict__ ci_drug,
                                             const float* __restrict__ ci_dis,
                                             const float* __restrict__ b) {
    const int per_side = NDRUG * (NCOL / 4);     // 4,000,000 float4 per side
    const int total = 2 * per_side;
    for (int idx = blockIdx.x * 256 + threadIdx.x; idx < total; idx += gridDim.x * 256) {
        int side = idx / per_side;
        int remi = idx - side * per_side;
        int n = remi / (NCOL / 4);
        int q = remi - n * (NCOL / 4);
        int col = q << 2;
        int o = col & 63;
        float ci = side ? ci_dis[n] : ci_drug[n];
        float4 bb = *(const float4*)(b + o);
        float4* p = (float4*)outp + idx;
        float4 v = *p;
        v.x = v.x * ci + bb.x;
        v.y = v.y * ci + bb.y;
        v.z = v.z * ci + bb.z;
        v.w = v.w * ci + bb.w;
        *p = v;
    }
}

// ---------------------------------------------------------------------------
extern "C" void kernel_launch(void* const* d_in, const int* in_sizes, int n_in,
                              void* d_out, int out_size, void* d_ws, size_t ws_size,
                              hipStream_t stream) {
    const float* drug_feat = (const float*)d_in[0];
    const float* dis_feat  = (const float*)d_in[1];
    const float* cj_drug   = (const float*)d_in[2];
    const float* ci_drug   = (const float*)d_in[3];
    const float* cj_dis    = (const float*)d_in[4];
    const float* ci_dis    = (const float*)d_in[5];
    const float* att       = (const float*)d_in[6];
    const float* basis     = (const float*)d_in[7];
    const float* fcw       = (const float*)d_in[8];
    const float* fcb       = (const float*)d_in[9];
    const int*   edge_drug = (const int*)d_in[10];
    const int*   edge_dis  = (const int*)d_in[11];

    float* out      = (float*)d_out;
    float* out_drug = out;
    float* out_dis  = out + (size_t)NDRUG * NCOL;

    // Workspace layout (needs ~128.2 MB):
    //   g_drug: 50000*320*4 = 64,000,000 B
    //   g_dis : 64,000,000 B
    //   M     : 128*320*4   = 163,840 B
    char* ws = (char*)d_ws;
    float* g_drug = (float*)ws;
    float* g_dis  = (float*)(ws + 64000000);
    float* Mbuf   = (float*)(ws + 128000000);

    // Zero output (atomic accumulation target)
    hipMemsetAsync(d_out, 0, (size_t)2 * NDRUG * NCOL * sizeof(float), stream);

    // A: fused att*basis*fc_w -> M [128][320]
    k_make_M<<<dim3((RR * FF * OUTD + 255) / 256), 256, 0, stream>>>(att, basis, fcw, Mbuf);

    // B: g = (feat @ M) * cj, both sides
    dim3 ggrid((NDRUG + 63) / 64, NCOL / 64, 2);
    k_gemm<<<ggrid, 256, 0, stream>>>(drug_feat, cj_drug, dis_feat, cj_dis, Mbuf, g_drug, g_dis);

    // C: edge aggregation (drug->dis into out_dis, dis->drug into out_drug)
    k_agg<<<2048, 256, 0, stream>>>(g_drug, edge_drug, edge_dis, out_dis);
    k_agg<<<2048, 256, 0, stream>>>(g_dis, edge_dis, edge_drug, out_drug);

    // D: scale by ci and add bias
    k_epi<<<2048, 256, 0, stream>>>(out, ci_drug, ci_dis, fcb);
}

// Round 2
// 990.199 us; speedup vs baseline: 1.0942x; 1.0942x over previous
//
#include <hip/hip_runtime.h>

// Problem constants
#define NDRUG 50000
#define NDIS  50000
#define RR    5
#define FF    128
#define EFFD  128
#define OUTD  64
#define EE    400000
#define NCOL  (RR * OUTD)        // 320 columns in fused g / out layout [n][r*64+o]
#define NB    (RR * NDIS)        // 250000 bins per direction
#define NEDGE (RR * EE)          // 2,000,000 edges per direction
#define NCHUNKS 500              // 2*NB / 1000 chunks of 1000 (dir boundary at chunk 250)

typedef unsigned short ushort_t;
typedef unsigned int uint_t;

// f32 -> bf16 round-to-nearest-even
static __device__ __forceinline__ ushort_t f2bf(float f) {
    uint_t u = __float_as_uint(f);
    uint_t r = (u + 0x7FFFu + ((u >> 16) & 1u)) >> 16;
    return (ushort_t)r;
}
static __device__ __forceinline__ float bf2f(ushort_t u) {
    return __uint_as_float(((uint_t)u) << 16);
}

// ---------------------------------------------------------------------------
// Kernel A: M[f][r*64+o] = sum_e (att[r,0]*basis[0,f,e]+att[r,1]*basis[1,f,e]) * fc_w[e,o]
// ---------------------------------------------------------------------------
__global__ __launch_bounds__(256) void k_make_M(const float* __restrict__ att,
                                                const float* __restrict__ basis,
                                                const float* __restrict__ fcw,
                                                float* __restrict__ M) {
    int tid = blockIdx.x * 256 + threadIdx.x;
    if (tid >= RR * FF * OUTD) return;
    int r = tid / (FF * OUTD);
    int rem = tid - r * FF * OUTD;
    int f = rem >> 6;
    int o = rem & 63;
    float a0 = att[r * 2 + 0], a1 = att[r * 2 + 1];
    const float* b0 = basis + f * EFFD;
    const float* b1 = basis + FF * EFFD + f * EFFD;
    float acc = 0.f;
#pragma unroll 4
    for (int e = 0; e < EFFD; ++e) {
        float w = a0 * b0[e] + a1 * b1[e];
        acc += w * fcw[e * OUTD + o];
    }
    M[f * NCOL + r * OUTD + o] = acc;
}

// ---------------------------------------------------------------------------
// Kernel B: g[n][col] = bf16( cj[n] * sum_k feat[n][k] * M[k][col] )
// 64x64 tile, 256 threads, 4x4 microtile. blockIdx.z selects drug/dis side.
// ---------------------------------------------------------------------------
__global__ __launch_bounds__(256) void k_gemm(const float* __restrict__ featA,
                                              const float* __restrict__ cjA,
                                              const float* __restrict__ featB,
                                              const float* __restrict__ cjB,
                                              const float* __restrict__ M,
                                              ushort_t* __restrict__ gA,
                                              ushort_t* __restrict__ gB) {
    const float* feat; const float* cj; ushort_t* g;
    if (blockIdx.z == 0) { feat = featA; cj = cjA; g = gA; }
    else                 { feat = featB; cj = cjB; g = gB; }

    __shared__ float As[64][132];
    __shared__ float Bs[128][68];

    const int tid  = threadIdx.x;
    const int row0 = blockIdx.x * 64;
    const int col0 = blockIdx.y * 64;

    for (int i = tid; i < 64 * 32; i += 256) {
        int r  = i >> 5;
        int c4 = (i & 31) << 2;
        float4 v = make_float4(0.f, 0.f, 0.f, 0.f);
        int row = row0 + r;
        if (row < NDRUG) v = *(const float4*)(feat + (size_t)row * FF + c4);
        *(float4*)&As[r][c4] = v;
    }
    for (int i = tid; i < 128 * 16; i += 256) {
        int k  = i >> 4;
        int c4 = (i & 15) << 2;
        *(float4*)&Bs[k][c4] = *(const float4*)(M + k * NCOL + col0 + c4);
    }
    __syncthreads();

    const int ty = (tid >> 4) << 2;
    const int tx = (tid & 15) << 2;

    float acc[4][4] = {};
#define GSTEP(AI, AC, BV) \
    acc[AI][0] += (AC) * (BV).x; acc[AI][1] += (AC) * (BV).y; \
    acc[AI][2] += (AC) * (BV).z; acc[AI][3] += (AC) * (BV).w;

    for (int k = 0; k < 128; k += 4) {
        float4 a0 = *(const float4*)&As[ty + 0][k];
        float4 a1 = *(const float4*)&As[ty + 1][k];
        float4 a2 = *(const float4*)&As[ty + 2][k];
        float4 a3 = *(const float4*)&As[ty + 3][k];
        float4 b0 = *(const float4*)&Bs[k + 0][tx];
        float4 b1 = *(const float4*)&Bs[k + 1][tx];
        float4 b2 = *(const float4*)&Bs[k + 2][tx];
        float4 b3 = *(const float4*)&Bs[k + 3][tx];
        GSTEP(0, a0.x, b0) GSTEP(0, a0.y, b1) GSTEP(0, a0.z, b2) GSTEP(0, a0.w, b3)
        GSTEP(1, a1.x, b0) GSTEP(1, a1.y, b1) GSTEP(1, a1.z, b2) GSTEP(1, a1.w, b3)
        GSTEP(2, a2.x, b0) GSTEP(2, a2.y, b1) GSTEP(2, a2.z, b2) GSTEP(2, a2.w, b3)
        GSTEP(3, a3.x, b0) GSTEP(3, a3.y, b1) GSTEP(3, a3.z, b2) GSTEP(3, a3.w, b3)
    }
#undef GSTEP

#pragma unroll
    for (int i = 0; i < 4; ++i) {
        int row = row0 + ty + i;
        if (row < NDRUG) {
            float s = cj[row];
            ushort4 pk;
            pk.x = f2bf(acc[i][0] * s);
            pk.y = f2bf(acc[i][1] * s);
            pk.z = f2bf(acc[i][2] * s);
            pk.w = f2bf(acc[i][3] * s);
            *(ushort4*)(g + (size_t)row * NCOL + col0 + tx) = pk;
        }
    }
}

// ---------------------------------------------------------------------------
// CSR build: histogram -> chunked exclusive scan -> scatter
// bins layout: [dir][r*NDIS + dst], flat 2*NB ints.
// dir 0: drug->dis (dst = edge_dis, src = edge_drug)
// dir 1: dis->drug (dst = edge_drug, src = edge_dis)
// ---------------------------------------------------------------------------
__global__ __launch_bounds__(256) void k_hist(const int* __restrict__ ed,
                                              const int* __restrict__ ei,
                                              int* __restrict__ bins) {
    int dir = blockIdx.y;
    const int* dstarr = dir ? ed : ei;
    int* b = bins + dir * NB;
    for (int i = blockIdx.x * 256 + threadIdx.x; i < NEDGE; i += gridDim.x * 256) {
        int r = i / EE;
        atomicAdd(&b[r * NDIS + dstarr[i]], 1);
    }
}

__global__ __launch_bounds__(256) void k_scan1(const int* __restrict__ bins,
                                               int* __restrict__ partial) {
    int b = blockIdx.x;           // 0..499, chunk of 1000
    int base = b * 1000;
    int t = threadIdx.x;
    int s = 0;
#pragma unroll
    for (int j = 0; j < 4; ++j) {
        int k = t * 4 + j;
        if (k < 1000) s += bins[base + k];
    }
    __shared__ int lds[256];
    lds[t] = s;
    __syncthreads();
    for (int off = 128; off; off >>= 1) {
        if (t < off) lds[t] += lds[t + off];
        __syncthreads();
    }
    if (t == 0) partial[b] = lds[0];
}

__global__ __launch_bounds__(512) void k_scan2(const int* __restrict__ partial,
                                               int* __restrict__ cofs) {
    __shared__ int lds[NCHUNKS];
    int t = threadIdx.x;
    if (t < NCHUNKS) lds[t] = partial[t];
    __syncthreads();
    if (t < 2) {                   // independent scan per direction (250 chunks each)
        int acc = 0;
        for (int c = 0; c < 250; ++c) {
            int v = lds[t * 250 + c];
            cofs[t * 250 + c] = acc;
            acc += v;
        }
    }
}

__global__ __launch_bounds__(256) void k_scan3(int* __restrict__ bins,
                                               const int* __restrict__ cofs) {
    int b = blockIdx.x, t = threadIdx.x, base = b * 1000;
    int v[4]; int mysum = 0;
#pragma unroll
    for (int j = 0; j < 4; ++j) {
        int k = t * 4 + j;
        v[j] = (k < 1000) ? bins[base + k] : 0;
        mysum += v[j];
    }
    __shared__ int lds[256];
    lds[t] = mysum;
    __syncthreads();
    for (int off = 1; off < 256; off <<= 1) {
        int x = (t >= off) ? lds[t - off] : 0;
        __syncthreads();
        lds[t] += x;
        __syncthreads();
    }
    int run = lds[t] - mysum + cofs[b];
#pragma unroll
    for (int j = 0; j < 4; ++j) {
        int k = t * 4 + j;
        if (k < 1000) { bins[base + k] = run; run += v[j]; }
    }
}

__global__ __launch_bounds__(256) void k_scatter(const int* __restrict__ ed,
                                                 const int* __restrict__ ei,
                                                 int* __restrict__ bins,
                                                 ushort_t* __restrict__ sorted) {
    int dir = blockIdx.y;
    const int* dstarr = dir ? ed : ei;
    const int* srcarr = dir ? ei : ed;
    int* b = bins + dir * NB;
    ushort_t* s = sorted + (size_t)dir * NEDGE;
    for (int i = blockIdx.x * 256 + threadIdx.x; i < NEDGE; i += gridDim.x * 256) {
        int r = i / EE;
        int pos = atomicAdd(&b[r * NDIS + dstarr[i]], 1);
        s[pos] = (ushort_t)srcarr[i];
    }
}

// ---------------------------------------------------------------------------
// Gather aggregation + fused epilogue. One wave per (dst, r) bin.
// After scatter, bins[dir][k] = inclusive end of bin k; start = bins[k-1] (0 for k=0).
// ---------------------------------------------------------------------------
__global__ __launch_bounds__(256) void k_agg(const ushort_t* __restrict__ gd,
                                             const ushort_t* __restrict__ gi,
                                             const int* __restrict__ bins,
                                             const ushort_t* __restrict__ sorted,
                                             const float* __restrict__ ci_drug,
                                             const float* __restrict__ ci_dis,
                                             const float* __restrict__ fcb,
                                             float* __restrict__ out_drug,
                                             float* __restrict__ out_dis) {
    int dir = blockIdx.y;
    const ushort_t* g   = dir ? gi : gd;
    const float* ci     = dir ? ci_drug : ci_dis;
    float* outp         = dir ? out_drug : out_dis;
    const int* bn       = bins + dir * NB;
    const ushort_t* srt = sorted + (size_t)dir * NEDGE;

    int wave = blockIdx.x * 4 + (threadIdx.x >> 6);
    int lane = threadIdx.x & 63;
    if (wave >= NB) return;
    int r = wave / NDIS;
    int dst = wave - r * NDIS;
    int start = wave ? bn[wave - 1] : 0;
    int end = bn[wave];

    int colbase = r * OUTD + lane;
    float acc = 0.f;
    for (int i = start; i < end; ++i) {
        int src = srt[i];
        acc += bf2f(g[(size_t)src * NCOL + colbase]);
    }
    outp[(size_t)dst * NCOL + colbase] = acc * ci[dst] + fcb[lane];
}

// ---------------------------------------------------------------------------
extern "C" void kernel_launch(void* const* d_in, const int* in_sizes, int n_in,
                              void* d_out, int out_size, void* d_ws, size_t ws_size,
                              hipStream_t stream) {
    const float* drug_feat = (const float*)d_in[0];
    const float* dis_feat  = (const float*)d_in[1];
    const float* cj_drug   = (const float*)d_in[2];
    const float* ci_drug   = (const float*)d_in[3];
    const float* cj_dis    = (const float*)d_in[4];
    const float* ci_dis    = (const float*)d_in[5];
    const float* att       = (const float*)d_in[6];
    const float* basis     = (const float*)d_in[7];
    const float* fcw       = (const float*)d_in[8];
    const float* fcb       = (const float*)d_in[9];
    const int*   edge_drug = (const int*)d_in[10];
    const int*   edge_dis  = (const int*)d_in[11];

    float* out      = (float*)d_out;
    float* out_drug = out;
    float* out_dis  = out + (size_t)NDRUG * NCOL;

    // Workspace layout (~74.2 MB):
    //   gd (bf16)  : 50000*320*2 = 32,000,000 B @ 0
    //   gi (bf16)  : 32,000,000 B            @ 32,000,000
    //   M  (f32)   : 163,840 B               @ 64,000,000
    //   bins (int) : 2*250000*4 = 2,000,000  @ 64,200,000
    //   partial    : 500*4                   @ 66,200,000
    //   cofs       : 500*4                   @ 66,204,000
    //   sorted     : 2*2,000,000*2 = 8 MB    @ 66,208,000
    char* ws = (char*)d_ws;
    ushort_t* gd      = (ushort_t*)ws;
    ushort_t* gi      = (ushort_t*)(ws + 32000000);
    float*    Mbuf    = (float*)(ws + 64000000);
    int*      bins    = (int*)(ws + 64200000);
    int*      partial = (int*)(ws + 66200000);
    int*      cofs    = (int*)(ws + 66204000);
    ushort_t* sorted  = (ushort_t*)(ws + 66208000);

    // zero histogram
    hipMemsetAsync(bins, 0, 2 * NB * sizeof(int), stream);

    // A: fused att*basis*fc_w -> M [128][320]
    k_make_M<<<dim3((RR * FF * OUTD + 255) / 256), 256, 0, stream>>>(att, basis, fcw, Mbuf);

    // B: g = bf16((feat @ M) * cj), both sides
    dim3 ggrid((NDRUG + 63) / 64, NCOL / 64, 2);
    k_gemm<<<ggrid, 256, 0, stream>>>(drug_feat, cj_drug, dis_feat, cj_dis, Mbuf, gd, gi);

    // CSR build
    k_hist<<<dim3(2048, 2), 256, 0, stream>>>(edge_drug, edge_dis, bins);
    k_scan1<<<NCHUNKS, 256, 0, stream>>>(bins, partial);
    k_scan2<<<1, 512, 0, stream>>>(partial, cofs);
    k_scan3<<<NCHUNKS, 256, 0, stream>>>(bins, cofs);
    k_scatter<<<dim3(2048, 2), 256, 0, stream>>>(edge_drug, edge_dis, bins, sorted);

    // Gather aggregation + fused ci-scale + bias
    k_agg<<<dim3((NB + 3) / 4, 2), 256, 0, stream>>>(gd, gi, bins, sorted,
                                                     ci_drug, ci_dis, fcb,
                                                     out_drug, out_dis);
}

// Round 3
// 794.639 us; speedup vs baseline: 1.3634x; 1.2461x over previous
//
#include <hip/hip_runtime.h>

// Problem constants
#define NDRUG 50000
#define NDIS  50000
#define RR    5
#define FF    128
#define EFFD  128
#define OUTD  64
#define EE    400000
#define NCOL  (RR * OUTD)        // 320 columns in fused g / out layout [n][r*64+o]
#define NB    (RR * NDIS)        // 250000 bins per direction
#define NEDGE (RR * EE)          // 2,000,000 edges per direction
#define NCHUNKS 500              // 2*NB / 1000 chunks of 1000 (dir boundary at chunk 250)

typedef unsigned short ushort_t;
typedef unsigned int uint_t;

// f32 -> bf16 round-to-nearest-even
static __device__ __forceinline__ ushort_t f2bf(float f) {
    uint_t u = __float_as_uint(f);
    uint_t r = (u + 0x7FFFu + ((u >> 16) & 1u)) >> 16;
    return (ushort_t)r;
}
static __device__ __forceinline__ float bf2f(ushort_t u) {
    return __uint_as_float(((uint_t)u) << 16);
}

// ---------------------------------------------------------------------------
// Kernel A: M[f][r*64+o] = sum_e (att[r,0]*basis[0,f,e]+att[r,1]*basis[1,f,e]) * fc_w[e,o]
// ---------------------------------------------------------------------------
__global__ __launch_bounds__(256) void k_make_M(const float* __restrict__ att,
                                                const float* __restrict__ basis,
                                                const float* __restrict__ fcw,
                                                float* __restrict__ M) {
    int tid = blockIdx.x * 256 + threadIdx.x;
    if (tid >= RR * FF * OUTD) return;
    int r = tid / (FF * OUTD);
    int rem = tid - r * FF * OUTD;
    int f = rem >> 6;
    int o = rem & 63;
    float a0 = att[r * 2 + 0], a1 = att[r * 2 + 1];
    const float* b0 = basis + f * EFFD;
    const float* b1 = basis + FF * EFFD + f * EFFD;
    float acc = 0.f;
#pragma unroll 4
    for (int e = 0; e < EFFD; ++e) {
        float w = a0 * b0[e] + a1 * b1[e];
        acc += w * fcw[e * OUTD + o];
    }
    M[f * NCOL + r * OUTD + o] = acc;
}

// ---------------------------------------------------------------------------
// Kernel B: g[n][col] = bf16( cj[n] * sum_k feat[n][k] * M[k][col] )
// 64x64 tile, 256 threads, 4x4 microtile. blockIdx.z selects drug/dis side.
// ---------------------------------------------------------------------------
__global__ __launch_bounds__(256) void k_gemm(const float* __restrict__ featA,
                                              const float* __restrict__ cjA,
                                              const float* __restrict__ featB,
                                              const float* __restrict__ cjB,
                                              const float* __restrict__ M,
                                              ushort_t* __restrict__ gA,
                                              ushort_t* __restrict__ gB) {
    const float* feat; const float* cj; ushort_t* g;
    if (blockIdx.z == 0) { feat = featA; cj = cjA; g = gA; }
    else                 { feat = featB; cj = cjB; g = gB; }

    __shared__ float As[64][132];
    __shared__ float Bs[128][68];

    const int tid  = threadIdx.x;
    const int row0 = blockIdx.x * 64;
    const int col0 = blockIdx.y * 64;

    for (int i = tid; i < 64 * 32; i += 256) {
        int r  = i >> 5;
        int c4 = (i & 31) << 2;
        float4 v = make_float4(0.f, 0.f, 0.f, 0.f);
        int row = row0 + r;
        if (row < NDRUG) v = *(const float4*)(feat + (size_t)row * FF + c4);
        *(float4*)&As[r][c4] = v;
    }
    for (int i = tid; i < 128 * 16; i += 256) {
        int k  = i >> 4;
        int c4 = (i & 15) << 2;
        *(float4*)&Bs[k][c4] = *(const float4*)(M + k * NCOL + col0 + c4);
    }
    __syncthreads();

    const int ty = (tid >> 4) << 2;
    const int tx = (tid & 15) << 2;

    float acc[4][4] = {};
#define GSTEP(AI, AC, BV) \
    acc[AI][0] += (AC) * (BV).x; acc[AI][1] += (AC) * (BV).y; \
    acc[AI][2] += (AC) * (BV).z; acc[AI][3] += (AC) * (BV).w;

    for (int k = 0; k < 128; k += 4) {
        float4 a0 = *(const float4*)&As[ty + 0][k];
        float4 a1 = *(const float4*)&As[ty + 1][k];
        float4 a2 = *(const float4*)&As[ty + 2][k];
        float4 a3 = *(const float4*)&As[ty + 3][k];
        float4 b0 = *(const float4*)&Bs[k + 0][tx];
        float4 b1 = *(const float4*)&Bs[k + 1][tx];
        float4 b2 = *(const float4*)&Bs[k + 2][tx];
        float4 b3 = *(const float4*)&Bs[k + 3][tx];
        GSTEP(0, a0.x, b0) GSTEP(0, a0.y, b1) GSTEP(0, a0.z, b2) GSTEP(0, a0.w, b3)
        GSTEP(1, a1.x, b0) GSTEP(1, a1.y, b1) GSTEP(1, a1.z, b2) GSTEP(1, a1.w, b3)
        GSTEP(2, a2.x, b0) GSTEP(2, a2.y, b1) GSTEP(2, a2.z, b2) GSTEP(2, a2.w, b3)
        GSTEP(3, a3.x, b0) GSTEP(3, a3.y, b1) GSTEP(3, a3.z, b2) GSTEP(3, a3.w, b3)
    }
#undef GSTEP

#pragma unroll
    for (int i = 0; i < 4; ++i) {
        int row = row0 + ty + i;
        if (row < NDRUG) {
            float s = cj[row];
            ushort4 pk;
            pk.x = f2bf(acc[i][0] * s);
            pk.y = f2bf(acc[i][1] * s);
            pk.z = f2bf(acc[i][2] * s);
            pk.w = f2bf(acc[i][3] * s);
            *(ushort4*)(g + (size_t)row * NCOL + col0 + tx) = pk;
        }
    }
}

// ---------------------------------------------------------------------------
// CSR build: histogram -> chunked exclusive scan -> scatter
// bins layout: [dir][r*NDIS + dst], flat 2*NB ints.
// dir 0: drug->dis (dst = edge_dis, src = edge_drug)
// dir 1: dis->drug (dst = edge_drug, src = edge_dis)
// grid: (chunks, RR, 2)
// ---------------------------------------------------------------------------
__global__ __launch_bounds__(256) void k_hist(const int* __restrict__ ed,
                                              const int* __restrict__ ei,
                                              int* __restrict__ bins) {
    int dir = blockIdx.z;
    int r = blockIdx.y;
    const int* dstarr = (dir ? ed : ei) + (size_t)r * EE;
    int* b = bins + dir * NB + r * NDIS;
    for (int i = blockIdx.x * 256 + threadIdx.x; i < EE; i += gridDim.x * 256)
        atomicAdd(&b[dstarr[i]], 1);
}

__global__ __launch_bounds__(256) void k_scan1(const int* __restrict__ bins,
                                               int* __restrict__ partial) {
    int b = blockIdx.x;           // 0..499, chunk of 1000
    int base = b * 1000;
    int t = threadIdx.x;
    int s = 0;
#pragma unroll
    for (int j = 0; j < 4; ++j) {
        int k = t * 4 + j;
        if (k < 1000) s += bins[base + k];
    }
    __shared__ int lds[256];
    lds[t] = s;
    __syncthreads();
    for (int off = 128; off; off >>= 1) {
        if (t < off) lds[t] += lds[t + off];
        __syncthreads();
    }
    if (t == 0) partial[b] = lds[0];
}

__global__ __launch_bounds__(512) void k_scan2(const int* __restrict__ partial,
                                               int* __restrict__ cofs) {
    __shared__ int lds[NCHUNKS];
    int t = threadIdx.x;
    if (t < NCHUNKS) lds[t] = partial[t];
    __syncthreads();
    if (t < 2) {                   // independent scan per direction (250 chunks each)
        int acc = 0;
        for (int c = 0; c < 250; ++c) {
            int v = lds[t * 250 + c];
            cofs[t * 250 + c] = acc;
            acc += v;
        }
    }
}

__global__ __launch_bounds__(256) void k_scan3(int* __restrict__ bins,
                                               const int* __restrict__ cofs) {
    int b = blockIdx.x, t = threadIdx.x, base = b * 1000;
    int v[4]; int mysum = 0;
#pragma unroll
    for (int j = 0; j < 4; ++j) {
        int k = t * 4 + j;
        v[j] = (k < 1000) ? bins[base + k] : 0;
        mysum += v[j];
    }
    __shared__ int lds[256];
    lds[t] = mysum;
    __syncthreads();
    for (int off = 1; off < 256; off <<= 1) {
        int x = (t >= off) ? lds[t - off] : 0;
        __syncthreads();
        lds[t] += x;
        __syncthreads();
    }
    int run = lds[t] - mysum + cofs[b];
#pragma unroll
    for (int j = 0; j < 4; ++j) {
        int k = t * 4 + j;
        if (k < 1000) { bins[base + k] = run; run += v[j]; }
    }
}

__global__ __launch_bounds__(256) void k_scatter(const int* __restrict__ ed,
                                                 const int* __restrict__ ei,
                                                 int* __restrict__ bins,
                                                 ushort_t* __restrict__ sorted) {
    int dir = blockIdx.z;
    int r = blockIdx.y;
    const int* dstarr = (dir ? ed : ei) + (size_t)r * EE;
    const int* srcarr = (dir ? ei : ed) + (size_t)r * EE;
    int* b = bins + dir * NB + r * NDIS;
    ushort_t* s = sorted + (size_t)dir * NEDGE;
    for (int i = blockIdx.x * 256 + threadIdx.x; i < EE; i += gridDim.x * 256) {
        int pos = atomicAdd(&b[dstarr[i]], 1);
        s[pos] = (ushort_t)srcarr[i];
    }
}

// ---------------------------------------------------------------------------
// Gather aggregation + fused epilogue. One wave per (dst, r) bin.
// After scatter, bins[dir][k] = inclusive end of bin k; start = bins[k-1] (0 for k=0).
// ILP: one wave-load grabs up to 64 src indices; __shfl broadcasts them so 8
// independent 128B gathers are in flight per group (predicated, clamped).
// ---------------------------------------------------------------------------
__global__ __launch_bounds__(256) void k_agg(const ushort_t* __restrict__ gd,
                                             const ushort_t* __restrict__ gi,
                                             const int* __restrict__ bins,
                                             const ushort_t* __restrict__ sorted,
                                             const float* __restrict__ ci_drug,
                                             const float* __restrict__ ci_dis,
                                             const float* __restrict__ fcb,
                                             float* __restrict__ out_drug,
                                             float* __restrict__ out_dis) {
    int dir = blockIdx.y;
    const ushort_t* g   = dir ? gi : gd;
    const float* ci     = dir ? ci_drug : ci_dis;
    float* outp         = dir ? out_drug : out_dis;
    const int* bn       = bins + dir * NB;
    const ushort_t* srt = sorted + (size_t)dir * NEDGE;

    int wave = blockIdx.x * 4 + (threadIdx.x >> 6);
    int lane = threadIdx.x & 63;
    if (wave >= NB) return;
    int r = wave / NDIS;
    int dst = wave - r * NDIS;
    int start = wave ? bn[wave - 1] : 0;
    int end = bn[wave];
    int colbase = r * OUTD + lane;

    float acc = 0.f;
    for (int base = start; base < end; base += 64) {
        int m = end - base; if (m > 64) m = 64;
        // one coalesced load: lane i holds src index of edge base+i (clamped)
        int li = lane < m ? lane : m - 1;
        int my = (int)srt[base + li];
        for (int j = 0; j < m; j += 8) {
            float part = 0.f;
#pragma unroll
            for (int k = 0; k < 8; ++k) {
                int jj = j + k;
                int cl = jj < m ? jj : m - 1;        // wave-uniform
                int sj = __shfl(my, cl);
                float v = bf2f(g[(size_t)sj * NCOL + colbase]);
                part += (jj < m) ? v : 0.f;
            }
            acc += part;
        }
    }
    outp[(size_t)dst * NCOL + colbase] = acc * ci[dst] + fcb[lane];
}

// ---------------------------------------------------------------------------
extern "C" void kernel_launch(void* const* d_in, const int* in_sizes, int n_in,
                              void* d_out, int out_size, void* d_ws, size_t ws_size,
                              hipStream_t stream) {
    const float* drug_feat = (const float*)d_in[0];
    const float* dis_feat  = (const float*)d_in[1];
    const float* cj_drug   = (const float*)d_in[2];
    const float* ci_drug   = (const float*)d_in[3];
    const float* cj_dis    = (const float*)d_in[4];
    const float* ci_dis    = (const float*)d_in[5];
    const float* att       = (const float*)d_in[6];
    const float* basis     = (const float*)d_in[7];
    const float* fcw       = (const float*)d_in[8];
    const float* fcb       = (const float*)d_in[9];
    const int*   edge_drug = (const int*)d_in[10];
    const int*   edge_dis  = (const int*)d_in[11];

    float* out      = (float*)d_out;
    float* out_drug = out;
    float* out_dis  = out + (size_t)NDRUG * NCOL;

    // Workspace layout (~74.2 MB):
    char* ws = (char*)d_ws;
    ushort_t* gd      = (ushort_t*)ws;
    ushort_t* gi      = (ushort_t*)(ws + 32000000);
    float*    Mbuf    = (float*)(ws + 64000000);
    int*      bins    = (int*)(ws + 64200000);
    int*      partial = (int*)(ws + 66200000);
    int*      cofs    = (int*)(ws + 66204000);
    ushort_t* sorted  = (ushort_t*)(ws + 66208000);

    // zero histogram
    hipMemsetAsync(bins, 0, 2 * NB * sizeof(int), stream);

    // A: fused att*basis*fc_w -> M [128][320]
    k_make_M<<<dim3((RR * FF * OUTD + 255) / 256), 256, 0, stream>>>(att, basis, fcw, Mbuf);

    // B: g = bf16((feat @ M) * cj), both sides
    dim3 ggrid((NDRUG + 63) / 64, NCOL / 64, 2);
    k_gemm<<<ggrid, 256, 0, stream>>>(drug_feat, cj_drug, dis_feat, cj_dis, Mbuf, gd, gi);

    // CSR build
    k_hist<<<dim3(512, RR, 2), 256, 0, stream>>>(edge_drug, edge_dis, bins);
    k_scan1<<<NCHUNKS, 256, 0, stream>>>(bins, partial);
    k_scan2<<<1, 512, 0, stream>>>(partial, cofs);
    k_scan3<<<NCHUNKS, 256, 0, stream>>>(bins, cofs);
    k_scatter<<<dim3(512, RR, 2), 256, 0, stream>>>(edge_drug, edge_dis, bins, sorted);

    // Gather aggregation + fused ci-scale + bias
    k_agg<<<dim3((NB + 3) / 4, 2), 256, 0, stream>>>(gd, gi, bins, sorted,
                                                     ci_drug, ci_dis, fcb,
                                                     out_drug, out_dis);
}

// Round 4
// 656.657 us; speedup vs baseline: 1.6499x; 1.2101x over previous
//
#include <hip/hip_runtime.h>

// Problem constants
#define NDRUG 50000
#define NDIS  50000
#define RR    5
#define FF    128
#define EFFD  128
#define OUTD  64
#define EE    400000
#define NCOL  (RR * OUTD)        // 320 columns in fused g / out layout [n][r*64+o]
#define NB    (RR * NDIS)        // 250000 bins per direction
#define NEDGE (RR * EE)          // 2,000,000 edges per direction
#define NCHUNKS 500              // 2*NB / 1000 chunks of 1000 (dir boundary at chunk 250)

// XCD partitioning for hist/scatter
#define NPART   8
#define DPART   (NDIS / NPART)   // 6250 dst per partition
#define NCHUNKE 64               // edge chunks per (r,dir)
#define CHUNKE  (EE / NCHUNKE)   // 6250 edges per chunk

typedef unsigned short ushort_t;
typedef unsigned int uint_t;

// f32 -> bf16 round-to-nearest-even
static __device__ __forceinline__ ushort_t f2bf(float f) {
    uint_t u = __float_as_uint(f);
    uint_t r = (u + 0x7FFFu + ((u >> 16) & 1u)) >> 16;
    return (ushort_t)r;
}
static __device__ __forceinline__ float bf2f(ushort_t u) {
    return __uint_as_float(((uint_t)u) << 16);
}

// ---------------------------------------------------------------------------
// Kernel A: M[f][r*64+o] = sum_e (att[r,0]*basis[0,f,e]+att[r,1]*basis[1,f,e]) * fc_w[e,o]
// ---------------------------------------------------------------------------
__global__ __launch_bounds__(256) void k_make_M(const float* __restrict__ att,
                                                const float* __restrict__ basis,
                                                const float* __restrict__ fcw,
                                                float* __restrict__ M) {
    int tid = blockIdx.x * 256 + threadIdx.x;
    if (tid >= RR * FF * OUTD) return;
    int r = tid / (FF * OUTD);
    int rem = tid - r * FF * OUTD;
    int f = rem >> 6;
    int o = rem & 63;
    float a0 = att[r * 2 + 0], a1 = att[r * 2 + 1];
    const float* b0 = basis + f * EFFD;
    const float* b1 = basis + FF * EFFD + f * EFFD;
    float acc = 0.f;
#pragma unroll 4
    for (int e = 0; e < EFFD; ++e) {
        float w = a0 * b0[e] + a1 * b1[e];
        acc += w * fcw[e * OUTD + o];
    }
    M[f * NCOL + r * OUTD + o] = acc;
}

// ---------------------------------------------------------------------------
// Kernel B: g[n][col] = bf16( cj[n] * sum_k feat[n][k] * M[k][col] )
// 64x64 tile, 256 threads, 4x4 microtile. blockIdx.z selects drug/dis side.
// ---------------------------------------------------------------------------
__global__ __launch_bounds__(256) void k_gemm(const float* __restrict__ featA,
                                              const float* __restrict__ cjA,
                                              const float* __restrict__ featB,
                                              const float* __restrict__ cjB,
                                              const float* __restrict__ M,
                                              ushort_t* __restrict__ gA,
                                              ushort_t* __restrict__ gB) {
    const float* feat; const float* cj; ushort_t* g;
    if (blockIdx.z == 0) { feat = featA; cj = cjA; g = gA; }
    else                 { feat = featB; cj = cjB; g = gB; }

    __shared__ float As[64][132];
    __shared__ float Bs[128][68];

    const int tid  = threadIdx.x;
    const int row0 = blockIdx.x * 64;
    const int col0 = blockIdx.y * 64;

    for (int i = tid; i < 64 * 32; i += 256) {
        int r  = i >> 5;
        int c4 = (i & 31) << 2;
        float4 v = make_float4(0.f, 0.f, 0.f, 0.f);
        int row = row0 + r;
        if (row < NDRUG) v = *(const float4*)(feat + (size_t)row * FF + c4);
        *(float4*)&As[r][c4] = v;
    }
    for (int i = tid; i < 128 * 16; i += 256) {
        int k  = i >> 4;
        int c4 = (i & 15) << 2;
        *(float4*)&Bs[k][c4] = *(const float4*)(M + k * NCOL + col0 + c4);
    }
    __syncthreads();

    const int ty = (tid >> 4) << 2;
    const int tx = (tid & 15) << 2;

    float acc[4][4] = {};
#define GSTEP(AI, AC, BV) \
    acc[AI][0] += (AC) * (BV).x; acc[AI][1] += (AC) * (BV).y; \
    acc[AI][2] += (AC) * (BV).z; acc[AI][3] += (AC) * (BV).w;

    for (int k = 0; k < 128; k += 4) {
        float4 a0 = *(const float4*)&As[ty + 0][k];
        float4 a1 = *(const float4*)&As[ty + 1][k];
        float4 a2 = *(const float4*)&As[ty + 2][k];
        float4 a3 = *(const float4*)&As[ty + 3][k];
        float4 b0 = *(const float4*)&Bs[k + 0][tx];
        float4 b1 = *(const float4*)&Bs[k + 1][tx];
        float4 b2 = *(const float4*)&Bs[k + 2][tx];
        float4 b3 = *(const float4*)&Bs[k + 3][tx];
        GSTEP(0, a0.x, b0) GSTEP(0, a0.y, b1) GSTEP(0, a0.z, b2) GSTEP(0, a0.w, b3)
        GSTEP(1, a1.x, b0) GSTEP(1, a1.y, b1) GSTEP(1, a1.z, b2) GSTEP(1, a1.w, b3)
        GSTEP(2, a2.x, b0) GSTEP(2, a2.y, b1) GSTEP(2, a2.z, b2) GSTEP(2, a2.w, b3)
        GSTEP(3, a3.x, b0) GSTEP(3, a3.y, b1) GSTEP(3, a3.z, b2) GSTEP(3, a3.w, b3)
    }
#undef GSTEP

#pragma unroll
    for (int i = 0; i < 4; ++i) {
        int row = row0 + ty + i;
        if (row < NDRUG) {
            float s = cj[row];
            ushort4 pk;
            pk.x = f2bf(acc[i][0] * s);
            pk.y = f2bf(acc[i][1] * s);
            pk.z = f2bf(acc[i][2] * s);
            pk.w = f2bf(acc[i][3] * s);
            *(ushort4*)(g + (size_t)row * NCOL + col0 + tx) = pk;
        }
    }
}

// ---------------------------------------------------------------------------
// CSR build: XCD-partitioned histogram -> chunked exclusive scan -> scatter
// bins layout: [dir][r*NDIS + dst], flat 2*NB ints.
// dir 0: drug->dis (dst = edge_dis, src = edge_drug)
// dir 1: dis->drug (dst = edge_drug, src = edge_dis)
// grid: (NCHUNKE*NPART, RR, 2); partition p = blockIdx.x & 7 handles only
// dst in [p*DPART, (p+1)*DPART) -> all atomics/writes for a bin region come
// from one XCD (round-robin blockIdx->XCD, gridDim.x % 8 == 0).
// ---------------------------------------------------------------------------
__global__ __launch_bounds__(256) void k_hist(const int* __restrict__ ed,
                                              const int* __restrict__ ei,
                                              int* __restrict__ bins) {
    int dir = blockIdx.z;
    int r = blockIdx.y;
    int p = blockIdx.x & (NPART - 1);
    int chunk = blockIdx.x >> 3;
    const int* dstarr = (dir ? ed : ei) + (size_t)r * EE;
    int* b = bins + dir * NB + r * NDIS;
    int lo = p * DPART, hi = lo + DPART;
    int e0 = chunk * CHUNKE;
    for (int i = e0 + threadIdx.x; i < e0 + CHUNKE; i += 256) {
        int d = dstarr[i];
        if (d >= lo && d < hi) atomicAdd(&b[d], 1);
    }
}

__global__ __launch_bounds__(256) void k_scan1(const int* __restrict__ bins,
                                               int* __restrict__ partial) {
    int b = blockIdx.x;           // 0..499, chunk of 1000
    int base = b * 1000;
    int t = threadIdx.x;
    int s = 0;
#pragma unroll
    for (int j = 0; j < 4; ++j) {
        int k = t * 4 + j;
        if (k < 1000) s += bins[base + k];
    }
    __shared__ int lds[256];
    lds[t] = s;
    __syncthreads();
    for (int off = 128; off; off >>= 1) {
        if (t < off) lds[t] += lds[t + off];
        __syncthreads();
    }
    if (t == 0) partial[b] = lds[0];
}

__global__ __launch_bounds__(512) void k_scan2(const int* __restrict__ partial,
                                               int* __restrict__ cofs) {
    __shared__ int lds[NCHUNKS];
    int t = threadIdx.x;
    if (t < NCHUNKS) lds[t] = partial[t];
    __syncthreads();
    if (t < 2) {                   // independent scan per direction (250 chunks each)
        int acc = 0;
        for (int c = 0; c < 250; ++c) {
            int v = lds[t * 250 + c];
            cofs[t * 250 + c] = acc;
            acc += v;
        }
    }
}

__global__ __launch_bounds__(256) void k_scan3(int* __restrict__ bins,
                                               const int* __restrict__ cofs) {
    int b = blockIdx.x, t = threadIdx.x, base = b * 1000;
    int v[4]; int mysum = 0;
#pragma unroll
    for (int j = 0; j < 4; ++j) {
        int k = t * 4 + j;
        v[j] = (k < 1000) ? bins[base + k] : 0;
        mysum += v[j];
    }
    __shared__ int lds[256];
    lds[t] = mysum;
    __syncthreads();
    for (int off = 1; off < 256; off <<= 1) {
        int x = (t >= off) ? lds[t - off] : 0;
        __syncthreads();
        lds[t] += x;
        __syncthreads();
    }
    int run = lds[t] - mysum + cofs[b];
#pragma unroll
    for (int j = 0; j < 4; ++j) {
        int k = t * 4 + j;
        if (k < 1000) { bins[base + k] = run; run += v[j]; }
    }
}

__global__ __launch_bounds__(256) void k_scatter(const int* __restrict__ ed,
                                                 const int* __restrict__ ei,
                                                 int* __restrict__ bins,
                                                 ushort_t* __restrict__ sorted) {
    int dir = blockIdx.z;
    int r = blockIdx.y;
    int p = blockIdx.x & (NPART - 1);
    int chunk = blockIdx.x >> 3;
    const int* dstarr = (dir ? ed : ei) + (size_t)r * EE;
    const int* srcarr = (dir ? ei : ed) + (size_t)r * EE;
    int* b = bins + dir * NB + r * NDIS;
    ushort_t* s = sorted + (size_t)dir * NEDGE;
    int lo = p * DPART, hi = lo + DPART;
    int e0 = chunk * CHUNKE;
    for (int i = e0 + threadIdx.x; i < e0 + CHUNKE; i += 256) {
        int d = dstarr[i];
        if (d >= lo && d < hi) {
            int pos = atomicAdd(&b[d], 1);
            s[pos] = (ushort_t)srcarr[i];
        }
    }
}

// ---------------------------------------------------------------------------
// Gather aggregation + fused epilogue. One wave per (dst, r) bin.
// After scatter, bins[dir][k] = inclusive end of bin k; start = bins[k-1] (0 for k=0).
// ILP: one wave-load grabs up to 64 src indices; __shfl broadcasts them so 8
// independent 128B gathers are in flight per group (predicated, clamped).
// ---------------------------------------------------------------------------
__global__ __launch_bounds__(256) void k_agg(const ushort_t* __restrict__ gd,
                                             const ushort_t* __restrict__ gi,
                                             const int* __restrict__ bins,
                                             const ushort_t* __restrict__ sorted,
                                             const float* __restrict__ ci_drug,
                                             const float* __restrict__ ci_dis,
                                             const float* __restrict__ fcb,
                                             float* __restrict__ out_drug,
                                             float* __restrict__ out_dis) {
    int dir = blockIdx.y;
    const ushort_t* g   = dir ? gi : gd;
    const float* ci     = dir ? ci_drug : ci_dis;
    float* outp         = dir ? out_drug : out_dis;
    const int* bn       = bins + dir * NB;
    const ushort_t* srt = sorted + (size_t)dir * NEDGE;

    int wave = blockIdx.x * 4 + (threadIdx.x >> 6);
    int lane = threadIdx.x & 63;
    if (wave >= NB) return;
    int r = wave / NDIS;
    int dst = wave - r * NDIS;
    int start = wave ? bn[wave - 1] : 0;
    int end = bn[wave];
    int colbase = r * OUTD + lane;

    float acc = 0.f;
    for (int base = start; base < end; base += 64) {
        int m = end - base; if (m > 64) m = 64;
        // one coalesced load: lane i holds src index of edge base+i (clamped)
        int li = lane < m ? lane : m - 1;
        int my = (int)srt[base + li];
        for (int j = 0; j < m; j += 8) {
            float part = 0.f;
#pragma unroll
            for (int k = 0; k < 8; ++k) {
                int jj = j + k;
                int cl = jj < m ? jj : m - 1;        // wave-uniform
                int sj = __shfl(my, cl);
                float v = bf2f(g[(size_t)sj * NCOL + colbase]);
                part += (jj < m) ? v : 0.f;
            }
            acc += part;
        }
    }
    outp[(size_t)dst * NCOL + colbase] = acc * ci[dst] + fcb[lane];
}

// ---------------------------------------------------------------------------
extern "C" void kernel_launch(void* const* d_in, const int* in_sizes, int n_in,
                              void* d_out, int out_size, void* d_ws, size_t ws_size,
                              hipStream_t stream) {
    const float* drug_feat = (const float*)d_in[0];
    const float* dis_feat  = (const float*)d_in[1];
    const float* cj_drug   = (const float*)d_in[2];
    const float* ci_drug   = (const float*)d_in[3];
    const float* cj_dis    = (const float*)d_in[4];
    const float* ci_dis    = (const float*)d_in[5];
    const float* att       = (const float*)d_in[6];
    const float* basis     = (const float*)d_in[7];
    const float* fcw       = (const float*)d_in[8];
    const float* fcb       = (const float*)d_in[9];
    const int*   edge_drug = (const int*)d_in[10];
    const int*   edge_dis  = (const int*)d_in[11];

    float* out      = (float*)d_out;
    float* out_drug = out;
    float* out_dis  = out + (size_t)NDRUG * NCOL;

    // Workspace layout (~74.2 MB):
    char* ws = (char*)d_ws;
    ushort_t* gd      = (ushort_t*)ws;
    ushort_t* gi      = (ushort_t*)(ws + 32000000);
    float*    Mbuf    = (float*)(ws + 64000000);
    int*      bins    = (int*)(ws + 64200000);
    int*      partial = (int*)(ws + 66200000);
    int*      cofs    = (int*)(ws + 66204000);
    ushort_t* sorted  = (ushort_t*)(ws + 66208000);

    // zero histogram
    hipMemsetAsync(bins, 0, 2 * NB * sizeof(int), stream);

    // A: fused att*basis*fc_w -> M [128][320]
    k_make_M<<<dim3((RR * FF * OUTD + 255) / 256), 256, 0, stream>>>(att, basis, fcw, Mbuf);

    // B: g = bf16((feat @ M) * cj), both sides
    dim3 ggrid((NDRUG + 63) / 64, NCOL / 64, 2);
    k_gemm<<<ggrid, 256, 0, stream>>>(drug_feat, cj_drug, dis_feat, cj_dis, Mbuf, gd, gi);

    // CSR build (XCD-partitioned hist + scatter)
    k_hist<<<dim3(NCHUNKE * NPART, RR, 2), 256, 0, stream>>>(edge_drug, edge_dis, bins);
    k_scan1<<<NCHUNKS, 256, 0, stream>>>(bins, partial);
    k_scan2<<<1, 512, 0, stream>>>(partial, cofs);
    k_scan3<<<NCHUNKS, 256, 0, stream>>>(bins, cofs);
    k_scatter<<<dim3(NCHUNKE * NPART, RR, 2), 256, 0, stream>>>(edge_drug, edge_dis, bins, sorted);

    // Gather aggregation + fused ci-scale + bias
    k_agg<<<dim3((NB + 3) / 4, 2), 256, 0, stream>>>(gd, gi, bins, sorted,
                                                     ci_drug, ci_dis, fcb,
                                                     out_drug, out_dis);
}

// Round 5
// 590.870 us; speedup vs baseline: 1.8336x; 1.1113x over previous
//
#include <hip/hip_runtime.h>

// Problem constants
#define NDRUG 50000
#define NDIS  50000
#define RR    5
#define FF    128
#define EFFD  128
#define OUTD  64
#define EE    400000
#define NCOL  (RR * OUTD)        // 320 columns in fused g / out layout [n][r*64+o]
#define NB    (RR * NDIS)        // 250000 bins per direction
#define NEDGE (RR * EE)          // 2,000,000 edges per direction
#define NCHUNKS 500              // 2*NB / 1000 chunks of 1000 (dir boundary at chunk 250)

// XCD partitioning for hist/scatter
#define NPART   8
#define DPART   (NDIS / NPART)   // 6250 dst per partition
#define NCHUNKE 64               // edge chunks per (r,dir)
#define CHUNKE  (EE / NCHUNKE)   // 6250 edges per chunk

typedef unsigned short ushort_t;
typedef unsigned int uint_t;
typedef short short8 __attribute__((ext_vector_type(8)));
typedef float f32x4 __attribute__((ext_vector_type(4)));

// f32 -> bf16 round-to-nearest-even
static __device__ __forceinline__ ushort_t f2bf(float f) {
    uint_t u = __float_as_uint(f);
    uint_t r = (u + 0x7FFFu + ((u >> 16) & 1u)) >> 16;
    return (ushort_t)r;
}
static __device__ __forceinline__ float bf2f(ushort_t u) {
    return __uint_as_float(((uint_t)u) << 16);
}

// ---------------------------------------------------------------------------
// Kernel A: Mt[col][f] = bf16( sum_e (att[r,0]*basis[0,f,e]+att[r,1]*basis[1,f,e]) * fc_w[e,o] )
// col = r*64+o. Transposed+bf16 so the MFMA B-fragment is contiguous in k(=f).
// ---------------------------------------------------------------------------
__global__ __launch_bounds__(256) void k_make_M(const float* __restrict__ att,
                                                const float* __restrict__ basis,
                                                const float* __restrict__ fcw,
                                                ushort_t* __restrict__ Mt) {
    int tid = blockIdx.x * 256 + threadIdx.x;
    if (tid >= RR * FF * OUTD) return;
    int r = tid / (FF * OUTD);
    int rem = tid - r * FF * OUTD;
    int f = rem >> 6;
    int o = rem & 63;
    float a0 = att[r * 2 + 0], a1 = att[r * 2 + 1];
    const float* b0 = basis + f * EFFD;
    const float* b1 = basis + FF * EFFD + f * EFFD;
    float acc = 0.f;
#pragma unroll 4
    for (int e = 0; e < EFFD; ++e) {
        float w = a0 * b0[e] + a1 * b1[e];
        acc += w * fcw[e * OUTD + o];
    }
    Mt[(size_t)(r * OUTD + o) * FF + f] = f2bf(acc);
}

// ---------------------------------------------------------------------------
// Kernel B (MFMA): g[n][col] = bf16( cj[n] * sum_k feat[n][k] * M[k][col] )
// Block: 64 rows x 160 cols, 4 waves. blockIdx.y = col half, blockIdx.z = side.
// LDS: feat bf16 [64][136] (pad 136 -> bank stride 4, 2-way = free),
//      Mt slice [160][136]. 60.9 KB total -> 2 blocks/CU.
// Fragments (mfma_f32_16x16x32_bf16, m89-verified C layout):
//   A: lane l holds feat[row0 + (l&15)][ks*32 + (l>>4)*8 + 0..7]
//   B: lane l holds Mt[col0 + (l&15)][ks*32 + (l>>4)*8 + 0..7]
//   D: col = l&15, row = (l>>4)*4 + reg
// ---------------------------------------------------------------------------
__global__ __launch_bounds__(256) void k_gemm(const float* __restrict__ featA,
                                              const float* __restrict__ cjA,
                                              const float* __restrict__ featB,
                                              const float* __restrict__ cjB,
                                              const ushort_t* __restrict__ Mt,
                                              ushort_t* __restrict__ gA,
                                              ushort_t* __restrict__ gB) {
    const float* feat; const float* cj; ushort_t* g;
    if (blockIdx.z == 0) { feat = featA; cj = cjA; g = gA; }
    else                 { feat = featB; cj = cjB; g = gB; }

    __shared__ ushort_t featS[64][136];
    __shared__ ushort_t mtS[160][136];

    const int tid  = threadIdx.x;
    const int row0 = blockIdx.x * 64;
    const int ch0  = blockIdx.y * 160;    // column-half base

    // Stage feat tile: 64 rows x 128 f32 -> bf16 LDS
    for (int i = tid; i < 64 * 32; i += 256) {
        int r  = i >> 5;
        int c4 = (i & 31) << 2;
        float4 v = make_float4(0.f, 0.f, 0.f, 0.f);
        int row = row0 + r;
        if (row < NDRUG) v = *(const float4*)(feat + (size_t)row * FF + c4);
        ushort4 pk;
        pk.x = f2bf(v.x); pk.y = f2bf(v.y); pk.z = f2bf(v.z); pk.w = f2bf(v.w);
        *(ushort4*)&featS[r][c4] = pk;
    }
    // Stage Mt slice: 160 cols x 128 k (bf16, contiguous 256B rows)
    for (int i = tid; i < 160 * 16; i += 256) {
        int c  = i >> 4;        // col within slice
        int q8 = (i & 15) << 3; // ushort offset (16B chunks)
        *(short8*)&mtS[c][q8] = *(const short8*)(Mt + (size_t)(ch0 + c) * FF + q8);
    }
    __syncthreads();

    const int w = tid >> 6;      // wave 0..3 -> rows w*16..w*16+15
    const int l = tid & 63;
    const int lr = l & 15;       // fragment row/col index
    const int lg = l >> 4;       // k-group

    short8 afrag[4];
#pragma unroll
    for (int ks = 0; ks < 4; ++ks)
        afrag[ks] = *(const short8*)&featS[w * 16 + lr][ks * 32 + lg * 8];

    const int rbase = row0 + w * 16 + (lg << 2);
    float cjv[4];
#pragma unroll
    for (int rg = 0; rg < 4; ++rg)
        cjv[rg] = (rbase + rg < NDRUG) ? cj[rbase + rg] : 0.f;

#pragma unroll
    for (int n = 0; n < 10; ++n) {
        f32x4 c = {0.f, 0.f, 0.f, 0.f};
#pragma unroll
        for (int ks = 0; ks < 4; ++ks) {
            short8 b = *(const short8*)&mtS[n * 16 + lr][ks * 32 + lg * 8];
            c = __builtin_amdgcn_mfma_f32_16x16x32_bf16(afrag[ks], b, c, 0, 0, 0);
        }
        int col = ch0 + n * 16 + lr;
#pragma unroll
        for (int rg = 0; rg < 4; ++rg) {
            int row = rbase + rg;
            if (row < NDRUG)
                g[(size_t)row * NCOL + col] = f2bf(c[rg] * cjv[rg]);
        }
    }
}

// ---------------------------------------------------------------------------
// CSR build: XCD-partitioned histogram -> chunked exclusive scan -> scatter
// bins layout: [dir][r*NDIS + dst], flat 2*NB ints.
// dir 0: drug->dis (dst = edge_dis, src = edge_drug)
// dir 1: dis->drug (dst = edge_drug, src = edge_dis)
// grid: (NCHUNKE*NPART, RR, 2); partition p = blockIdx.x & 7 handles only
// dst in [p*DPART, (p+1)*DPART) -> all atomics/writes for a bin region come
// from one XCD (round-robin blockIdx->XCD, gridDim.x % 8 == 0).
// ---------------------------------------------------------------------------
__global__ __launch_bounds__(256) void k_hist(const int* __restrict__ ed,
                                              const int* __restrict__ ei,
                                              int* __restrict__ bins) {
    int dir = blockIdx.z;
    int r = blockIdx.y;
    int p = blockIdx.x & (NPART - 1);
    int chunk = blockIdx.x >> 3;
    const int* dstarr = (dir ? ed : ei) + (size_t)r * EE;
    int* b = bins + dir * NB + r * NDIS;
    int lo = p * DPART, hi = lo + DPART;
    int e0 = chunk * CHUNKE;
    for (int i = e0 + threadIdx.x; i < e0 + CHUNKE; i += 256) {
        int d = dstarr[i];
        if (d >= lo && d < hi) atomicAdd(&b[d], 1);
    }
}

__global__ __launch_bounds__(256) void k_scan1(const int* __restrict__ bins,
                                               int* __restrict__ partial) {
    int b = blockIdx.x;           // 0..499, chunk of 1000
    int base = b * 1000;
    int t = threadIdx.x;
    int s = 0;
#pragma unroll
    for (int j = 0; j < 4; ++j) {
        int k = t * 4 + j;
        if (k < 1000) s += bins[base + k];
    }
    __shared__ int lds[256];
    lds[t] = s;
    __syncthreads();
    for (int off = 128; off; off >>= 1) {
        if (t < off) lds[t] += lds[t + off];
        __syncthreads();
    }
    if (t == 0) partial[b] = lds[0];
}

__global__ __launch_bounds__(512) void k_scan2(const int* __restrict__ partial,
                                               int* __restrict__ cofs) {
    __shared__ int lds[NCHUNKS];
    int t = threadIdx.x;
    if (t < NCHUNKS) lds[t] = partial[t];
    __syncthreads();
    if (t < 2) {                   // independent scan per direction (250 chunks each)
        int acc = 0;
        for (int c = 0; c < 250; ++c) {
            int v = lds[t * 250 + c];
            cofs[t * 250 + c] = acc;
            acc += v;
        }
    }
}

__global__ __launch_bounds__(256) void k_scan3(int* __restrict__ bins,
                                               const int* __restrict__ cofs) {
    int b = blockIdx.x, t = threadIdx.x, base = b * 1000;
    int v[4]; int mysum = 0;
#pragma unroll
    for (int j = 0; j < 4; ++j) {
        int k = t * 4 + j;
        v[j] = (k < 1000) ? bins[base + k] : 0;
        mysum += v[j];
    }
    __shared__ int lds[256];
    lds[t] = mysum;
    __syncthreads();
    for (int off = 1; off < 256; off <<= 1) {
        int x = (t >= off) ? lds[t - off] : 0;
        __syncthreads();
        lds[t] += x;
        __syncthreads();
    }
    int run = lds[t] - mysum + cofs[b];
#pragma unroll
    for (int j = 0; j < 4; ++j) {
        int k = t * 4 + j;
        if (k < 1000) { bins[base + k] = run; run += v[j]; }
    }
}

__global__ __launch_bounds__(256) void k_scatter(const int* __restrict__ ed,
                                                 const int* __restrict__ ei,
                                                 int* __restrict__ bins,
                                                 ushort_t* __restrict__ sorted) {
    int dir = blockIdx.z;
    int r = blockIdx.y;
    int p = blockIdx.x & (NPART - 1);
    int chunk = blockIdx.x >> 3;
    const int* dstarr = (dir ? ed : ei) + (size_t)r * EE;
    const int* srcarr = (dir ? ei : ed) + (size_t)r * EE;
    int* b = bins + dir * NB + r * NDIS;
    ushort_t* s = sorted + (size_t)dir * NEDGE;
    int lo = p * DPART, hi = lo + DPART;
    int e0 = chunk * CHUNKE;
    for (int i = e0 + threadIdx.x; i < e0 + CHUNKE; i += 256) {
        int d = dstarr[i];
        if (d >= lo && d < hi) {
            int pos = atomicAdd(&b[d], 1);
            s[pos] = (ushort_t)srcarr[i];
        }
    }
}

// ---------------------------------------------------------------------------
// Gather aggregation + fused epilogue. One wave per (dst, r) bin.
// After scatter, bins[dir][k] = inclusive end of bin k; start = bins[k-1] (0 for k=0).
// ILP: one wave-load grabs up to 64 src indices; __shfl broadcasts them so 8
// independent 128B gathers are in flight per group (predicated, clamped).
// ---------------------------------------------------------------------------
__global__ __launch_bounds__(256) void k_agg(const ushort_t* __restrict__ gd,
                                             const ushort_t* __restrict__ gi,
                                             const int* __restrict__ bins,
                                             const ushort_t* __restrict__ sorted,
                                             const float* __restrict__ ci_drug,
                                             const float* __restrict__ ci_dis,
                                             const float* __restrict__ fcb,
                                             float* __restrict__ out_drug,
                                             float* __restrict__ out_dis) {
    int dir = blockIdx.y;
    const ushort_t* g   = dir ? gi : gd;
    const float* ci     = dir ? ci_drug : ci_dis;
    float* outp         = dir ? out_drug : out_dis;
    const int* bn       = bins + dir * NB;
    const ushort_t* srt = sorted + (size_t)dir * NEDGE;

    int wave = blockIdx.x * 4 + (threadIdx.x >> 6);
    int lane = threadIdx.x & 63;
    if (wave >= NB) return;
    int r = wave / NDIS;
    int dst = wave - r * NDIS;
    int start = wave ? bn[wave - 1] : 0;
    int end = bn[wave];
    int colbase = r * OUTD + lane;

    float acc = 0.f;
    for (int base = start; base < end; base += 64) {
        int m = end - base; if (m > 64) m = 64;
        // one coalesced load: lane i holds src index of edge base+i (clamped)
        int li = lane < m ? lane : m - 1;
        int my = (int)srt[base + li];
        for (int j = 0; j < m; j += 8) {
            float part = 0.f;
#pragma unroll
            for (int k = 0; k < 8; ++k) {
                int jj = j + k;
                int cl = jj < m ? jj : m - 1;        // wave-uniform
                int sj = __shfl(my, cl);
                float v = bf2f(g[(size_t)sj * NCOL + colbase]);
                part += (jj < m) ? v : 0.f;
            }
            acc += part;
        }
    }
    outp[(size_t)dst * NCOL + colbase] = acc * ci[dst] + fcb[lane];
}

// ---------------------------------------------------------------------------
extern "C" void kernel_launch(void* const* d_in, const int* in_sizes, int n_in,
                              void* d_out, int out_size, void* d_ws, size_t ws_size,
                              hipStream_t stream) {
    const float* drug_feat = (const float*)d_in[0];
    const float* dis_feat  = (const float*)d_in[1];
    const float* cj_drug   = (const float*)d_in[2];
    const float* ci_drug   = (const float*)d_in[3];
    const float* cj_dis    = (const float*)d_in[4];
    const float* ci_dis    = (const float*)d_in[5];
    const float* att       = (const float*)d_in[6];
    const float* basis     = (const float*)d_in[7];
    const float* fcw       = (const float*)d_in[8];
    const float* fcb       = (const float*)d_in[9];
    const int*   edge_drug = (const int*)d_in[10];
    const int*   edge_dis  = (const int*)d_in[11];

    float* out      = (float*)d_out;
    float* out_drug = out;
    float* out_dis  = out + (size_t)NDRUG * NCOL;

    // Workspace layout (~74.2 MB):
    char* ws = (char*)d_ws;
    ushort_t* gd      = (ushort_t*)ws;
    ushort_t* gi      = (ushort_t*)(ws + 32000000);
    ushort_t* Mtb     = (ushort_t*)(ws + 64000000);   // bf16 Mt [320][128]
    int*      bins    = (int*)(ws + 64200000);
    int*      partial = (int*)(ws + 66200000);
    int*      cofs    = (int*)(ws + 66204000);
    ushort_t* sorted  = (ushort_t*)(ws + 66208000);

    // zero histogram
    hipMemsetAsync(bins, 0, 2 * NB * sizeof(int), stream);

    // A: fused att*basis*fc_w -> Mt bf16 [320][128]
    k_make_M<<<dim3((RR * FF * OUTD + 255) / 256), 256, 0, stream>>>(att, basis, fcw, Mtb);

    // B: g = bf16((feat @ M) * cj), both sides (MFMA)
    dim3 ggrid((NDRUG + 63) / 64, 2, 2);
    k_gemm<<<ggrid, 256, 0, stream>>>(drug_feat, cj_drug, dis_feat, cj_dis, Mtb, gd, gi);

    // CSR build (XCD-partitioned hist + scatter)
    k_hist<<<dim3(NCHUNKE * NPART, RR, 2), 256, 0, stream>>>(edge_drug, edge_dis, bins);
    k_scan1<<<NCHUNKS, 256, 0, stream>>>(bins, partial);
    k_scan2<<<1, 512, 0, stream>>>(partial, cofs);
    k_scan3<<<NCHUNKS, 256, 0, stream>>>(bins, cofs);
    k_scatter<<<dim3(NCHUNKE * NPART, RR, 2), 256, 0, stream>>>(edge_drug, edge_dis, bins, sorted);

    // Gather aggregation + fused ci-scale + bias
    k_agg<<<dim3((NB + 3) / 4, 2), 256, 0, stream>>>(gd, gi, bins, sorted,
                                                     ci_drug, ci_dis, fcb,
                                                     out_drug, out_dis);
}